// Round 16
// baseline (336.036 us; speedup 1.0000x reference)
//
#include <hip/hip_runtime.h>
#include <hip/hip_bf16.h>
#include <stdint.h>

#define S_LEN 2048
#define HIDD  4096
#define NH    32
#define NKV   8
#define HD    128
#define NQKV  6144   // (NH + 2*NKV) * HD
#define ATT_SCALE 0.08838834764831845f
#define LOG2E 1.4426950408889634f

typedef unsigned short u16;
typedef __attribute__((ext_vector_type(8))) short short8;
typedef __attribute__((ext_vector_type(4))) float f32x4;

__device__ __forceinline__ unsigned f2bfbits(float f){
  union{float f; unsigned u;} v; v.f = f;
  return (v.u + 0x7FFFu + ((v.u>>16)&1u)) >> 16;
}
__device__ __forceinline__ float bf2f(u16 b){
  union{unsigned u; float f;} v; v.u = ((unsigned)b)<<16;
  return v.f;
}
__device__ __forceinline__ unsigned packbf(float a, float b){
  return f2bfbits(a) | (f2bfbits(b)<<16);
}
__device__ __forceinline__ unsigned cvtpk(float lo, float hi){
  unsigned r;
  asm("v_cvt_pk_bf16_f32 %0, %1, %2" : "=v"(r) : "v"(lo), "v"(hi));
  return r;
}

#define GLOAD16(g, l) __builtin_amdgcn_global_load_lds( \
    (__attribute__((address_space(1))) void*)(g), \
    (__attribute__((address_space(3))) void*)(l), 16, 0, 0)

#define VMWAIT(n) asm volatile("s_waitcnt vmcnt(" #n ")" ::: "memory")
#define SCHED0() __builtin_amdgcn_sched_barrier(0)

// -------- fp32 -> bf16 convert, 5 segments (X, Wq, Wk, Wv, Wo) in one launch
__global__ __launch_bounds__(256) void cvt_all(const float* __restrict__ hs,
                                               const float* __restrict__ Wq,
                                               const float* __restrict__ Wk,
                                               const float* __restrict__ Wv,
                                               const float* __restrict__ Wo,
                                               u16* __restrict__ Xb,
                                               u16* __restrict__ WQKV,
                                               u16* __restrict__ Wob){
  const float* src; u16* dst; int n8;
  switch (blockIdx.y){
    case 0: src = hs; dst = Xb;                        n8 = S_LEN*HIDD/8;    break;
    case 1: src = Wq; dst = WQKV;                      n8 = NH*HD*HIDD/8;    break;
    case 2: src = Wk; dst = WQKV + (size_t)NH*HD*HIDD; n8 = NKV*HD*HIDD/8;   break;
    case 3: src = Wv; dst = WQKV + (size_t)(NH+NKV)*HD*HIDD; n8 = NKV*HD*HIDD/8; break;
    default:src = Wo; dst = Wob;                       n8 = HIDD*NH*HD/8;    break;
  }
  int i = blockIdx.x*256 + threadIdx.x;
  if (i >= n8) return;
  const float4* p = (const float4*)src;
  float4 a = p[2*i], b = p[2*i+1];
  union { unsigned u[4]; short8 s; } o;
  o.u[0] = packbf(a.x, a.y); o.u[1] = packbf(a.z, a.w);
  o.u[2] = packbf(b.x, b.y); o.u[3] = packbf(b.z, b.w);
  *(short8*)(dst + (size_t)i*8) = o.s;
}

// ====== GEMM1 fused: QKV = X*WQKV^T then RMSNorm+RoPE+V-transpose epilogue ==
// 128x384 tile (BN = exactly 3 heads), grid 16x16 = 256 blocks (full fill),
// 8 waves (2M x 4N): per wave MREP=4, NF=6, 24 MFMA/phase, 10 ds_reads.
// 2 phases per K64-tile; stage-point = 4 gloads (A 1 + B 3) for region p+2;
// steady vmcnt(4) (retires last phase's SP = next phase's region), tail 0.
// Epilogue: acc -> bf16 C-tile in LDS (96KB), barrier, per-(row,head)
// RMSNorm+RoPE (Q scaled by ATT_SCALE*LOG2E) -> Qn/Kn, V transposed -> Vt.
__global__ __launch_bounds__(512) void gemm1_fused(const u16* __restrict__ A,
                                                   const u16* __restrict__ B,
                                                   const float* __restrict__ cosb,
                                                   const float* __restrict__ sinb,
                                                   const float* __restrict__ qw,
                                                   const float* __restrict__ kw,
                                                   u16* __restrict__ Qn,
                                                   u16* __restrict__ Kn,
                                                   u16* __restrict__ Vt){
  __shared__ __align__(16) char lds[131072];   // main: 32KB A + 96KB B regions

  const int tid = threadIdx.x;
  const int w = tid>>6, lane = tid&63, ln = lane&15, g = lane>>4;
  const int wm = w>>2, wn = w&3;
  const int swz5 = ((ln>>3)&1)<<5;
  const int K = HIDD;

  const int nwg = gridDim.x, flat = blockIdx.x;
  const int wg = (flat&7)*(nwg>>3) + (flat>>3);
  const int by = wg>>4, bx = wg&15;            // 16 x 16
  const int m0 = by*128, n0 = bx*384;

  const int rs   = ((tid>>6)<<4) + ((tid&63)>>2);
  const int ksrc = ((tid&3)<<3) ^ (((tid>>5)&1)<<4);
  const u16* srcA0 = A + (size_t)(m0 + rs)*K + ksrc;
  const u16* srcB[3];
  #pragma unroll
  for (int j=0;j<3;j++) srcB[j] = B + (size_t)(n0 + 128*j + rs)*K + ksrc;

  #define G1_AREG(bf,kh) (lds + ((bf)*2 + (kh))*8192)
  #define G1_BREG(bf,kh) (lds + 32768 + ((bf)*2 + (kh))*24576)

  #define G1_STAGE(T, kh, bf) { const int off_ = (T)*64 + (kh)*32;                \
    GLOAD16(srcA0 + off_, G1_AREG(bf,kh) + w*1024);                               \
    _Pragma("unroll") for (int j=0;j<3;j++)                                       \
      GLOAD16(srcB[j] + off_, G1_BREG(bf,kh) + j*8192 + w*1024); }

  f32x4 acc[4][6];
  #pragma unroll
  for (int m=0;m<4;m++)
    #pragma unroll
    for (int n=0;n<6;n++) acc[m][n] = (f32x4){0.f,0.f,0.f,0.f};
  short8 a_[4], b_[6];

  #define G1_READA(bf,kh) { _Pragma("unroll") for (int m=0;m<4;m++)               \
    a_[m] = *(const short8*)(G1_AREG(bf,kh) + (wm*4+m)*1024 + ln*64 + ((g*16)^swz5)); }
  #define G1_READB(bf,kh) { _Pragma("unroll") for (int n=0;n<6;n++)               \
    b_[n] = *(const short8*)(G1_BREG(bf,kh) + (wn*6+n)*1024 + ln*64 + ((g*16)^swz5)); }
  #define G1_MFMA() { __builtin_amdgcn_s_setprio(1);                              \
    _Pragma("unroll") for (int m=0;m<4;m++)                                       \
      _Pragma("unroll") for (int n=0;n<6;n++)                                     \
        acc[m][n] = __builtin_amdgcn_mfma_f32_16x16x32_bf16(a_[m], b_[n], acc[m][n], 0,0,0); \
    __builtin_amdgcn_s_setprio(0); }
  #define G1_BARR() __builtin_amdgcn_s_barrier()

  // prologue: regions (tile0,k0) and (tile0,k1); retire region0, region1 in flight
  G1_STAGE(0,0,0); G1_STAGE(0,1,0);
  VMWAIT(4); G1_BARR(); SCHED0();

  const int NT64 = K>>6;   // 64
  #pragma unroll 1
  for (int T=0; T<NT64; T+=2){
    // ---- tile T (buf 0) ----
    G1_READB(0,0); G1_READA(0,0); G1_STAGE(T+1, 0, 1);
    G1_MFMA();
    SCHED0(); VMWAIT(4); G1_BARR(); SCHED0();
    G1_READB(0,1); G1_READA(0,1); G1_STAGE(T+1, 1, 1);
    G1_MFMA();
    SCHED0(); VMWAIT(4); G1_BARR(); SCHED0();
    // ---- tile T+1 (buf 1) ----
    const bool s2 = (T+2) < NT64;
    G1_READB(1,0); G1_READA(1,0); if (s2) G1_STAGE(T+2, 0, 0);
    G1_MFMA();
    SCHED0(); if (s2) { VMWAIT(4); } else { VMWAIT(0); } G1_BARR(); SCHED0();
    G1_READB(1,1); G1_READA(1,1); if (s2) G1_STAGE(T+2, 1, 0);
    G1_MFMA();
    SCHED0(); if (s2) { VMWAIT(4); } else { VMWAIT(0); } G1_BARR(); SCHED0();
  }

  // ---------------- fused epilogue ----------------
  // write bf16 C-tile [128][384] into LDS (all main-loop reads are done: the
  // final barrier above orders every wave's ds_reads before these writes)
  u16* clds = (u16*)lds;
  #pragma unroll
  for (int m=0;m<4;m++)
    #pragma unroll
    for (int n=0;n<6;n++)
      #pragma unroll
      for (int r=0;r<4;r++){
        int row = wm*64 + m*16 + g*4 + r;
        int col = wn*96 + n*16 + ln;
        clds[row*384 + col] = (u16)f2bfbits(acc[m][n][r]);
      }
  G1_BARR();

  const float wq0 = qw[lane], wq1 = qw[lane+64];
  const float wk0 = kw[lane], wk1 = kw[lane+64];
  const float qsc = ATT_SCALE*LOG2E;

  #pragma unroll 1
  for (int r8=0; r8<16; ++r8){
    const int row = w*16 + r8;               // wave w owns rows w*16..+15
    const int s = m0 + row;
    const float c0 = cosb[(size_t)s*HD + lane];
    const float c1 = cosb[(size_t)s*HD + lane + 64];
    const float s0 = sinb[(size_t)s*HD + lane];
    const float s1 = sinb[(size_t)s*HD + lane + 64];
    #pragma unroll
    for (int lh=0; lh<3; ++lh){
      const int slot = 3*bx + lh;            // 0..31 Q, 32..39 K, 40..47 V
      float x0 = bf2f(clds[row*384 + lh*128 + lane]);
      float x1 = bf2f(clds[row*384 + lh*128 + lane + 64]);
      if (slot < 40){
        float ss = x0*x0 + x1*x1;
        #pragma unroll
        for (int off=1; off<64; off<<=1) ss += __shfl_xor(ss, off, 64);
        float rr = rsqrtf(ss*(1.0f/128.0f) + 1e-6f);
        bool isq = slot < 32;
        float y0 = x0*rr*(isq ? wq0 : wk0);
        float y1 = x1*rr*(isq ? wq1 : wk1);
        float o0 = y0*c0 - y1*s0;
        float o1 = y1*c1 + y0*s1;
        float sc = isq ? qsc : 1.0f;
        u16* dst = isq ? (Qn + ((size_t)slot*S_LEN + s)*HD)
                       : (Kn + ((size_t)(slot-32)*S_LEN + s)*HD);
        dst[lane]    = (u16)f2bfbits(o0*sc);
        dst[lane+64] = (u16)f2bfbits(o1*sc);
      } else {
        int kvh = slot - 40;
        u16* dst = Vt + (size_t)kvh*HD*S_LEN + s;
        dst[(size_t)lane*S_LEN]      = (u16)f2bfbits(x0);
        dst[(size_t)(lane+64)*S_LEN] = (u16)f2bfbits(x1);
      }
    }
  }
  #undef G1_AREG
  #undef G1_BREG
  #undef G1_STAGE
  #undef G1_READA
  #undef G1_READB
  #undef G1_MFMA
  #undef G1_BARR
}

// ============ 4-phase GEMM with register-fragment pipeline (round-12) =======
template<int BM, int BN, typename OT>
__global__ __launch_bounds__(512) void gemm_4ph(const u16* __restrict__ A,
                                                const u16* __restrict__ B,
                                                OT* __restrict__ C,
                                                int N, int K, int nbx){
  constexpr int MREP = BM/32;
  constexpr int NF   = BN/64;
  constexpr int AH   = BM/128;
  constexpr int ASZ  = BM*64;
  __shared__ __align__(16) char lds[4*ASZ + 65536];

  const int tid = threadIdx.x;
  const int w = tid>>6, lane = tid&63, ln = lane&15, g = lane>>4;
  const int wm = w>>2, wn = w&3;
  const int swz5 = ((ln>>3)&1)<<5;

  const int nwg = gridDim.x, flat = blockIdx.x;
  const int wg = (flat&7)*(nwg>>3) + (flat>>3);
  const int by = wg/nbx, bx = wg - by*nbx;
  const int m0 = by*BM, n0 = bx*BN;

  const int rs   = ((tid>>6)<<4) + ((tid&63)>>2);
  const int ksrc = ((tid&3)<<3) ^ (((tid>>5)&1)<<4);
  const u16* srcA[AH];
  #pragma unroll
  for (int h=0;h<AH;h++) srcA[h] = A + (size_t)(m0 + h*128 + rs)*K + ksrc;
  const u16* srcB[2];
  #pragma unroll
  for (int h=0;h<2;h++)  srcB[h] = B + (size_t)(n0 + h*128 + rs)*K + ksrc;

  #define AREG(bf,kh) (lds + ((bf)*2 + (kh))*ASZ)
  #define BREG(bf,kh) (lds + 4*ASZ + ((bf)*2 + (kh))*16384)

  #define STAGEPT(t, kh, bf) { const int off_ = (t)*64 + (kh)*32;                 \
    _Pragma("unroll") for (int h=0;h<AH;h++)                                      \
      GLOAD16(srcA[h]+off_, AREG(bf,kh) + h*8192 + w*1024);                       \
    _Pragma("unroll") for (int h=0;h<2;h++)                                       \
      GLOAD16(srcB[h]+off_, BREG(bf,kh) + h*8192 + w*1024); }

  f32x4 acc[MREP][NF];
  #pragma unroll
  for (int m=0;m<MREP;m++)
    #pragma unroll
    for (int n=0;n<NF;n++) acc[m][n] = (f32x4){0.f,0.f,0.f,0.f};
  short8 a0_[MREP], b0_[NF], a1_[MREP], b1_[NF];

  #define READ_SET(aset, bset, bf, kh) {                                          \
    _Pragma("unroll") for (int n=0;n<NF;n++)                                      \
      bset[n] = *(const short8*)(BREG(bf,kh) + (wn*NF+n)*1024 + ln*64 + ((g*16)^swz5)); \
    _Pragma("unroll") for (int m=0;m<MREP;m++)                                    \
      aset[m] = *(const short8*)(AREG(bf,kh) + (wm*MREP+m)*1024 + ln*64 + ((g*16)^swz5)); }
  #define MFMA_SET(aset, bset) { __builtin_amdgcn_s_setprio(1);                   \
    _Pragma("unroll") for (int m=0;m<MREP;m++)                                    \
      _Pragma("unroll") for (int n=0;n<NF;n++)                                    \
        acc[m][n] = __builtin_amdgcn_mfma_f32_16x16x32_bf16(aset[m], bset[n], acc[m][n], 0,0,0); \
    __builtin_amdgcn_s_setprio(0); }
  #define BARR() __builtin_amdgcn_s_barrier()
  #define VMST() do{ if constexpr (AH==2) { VMWAIT(4); } else { VMWAIT(3); } }while(0)

  STAGEPT(0,0,0); STAGEPT(0,1,0); STAGEPT(1,0,1);
  VMWAIT(0); BARR(); SCHED0();
  READ_SET(a0_, b0_, 0, 0);

  const int NIT = K>>7;
  #pragma unroll 1
  for (int it=0; it<NIT; ++it){
    const bool last = (it == NIT-1);
    const int t0 = 2*it;
    READ_SET(a1_, b1_, 0, 1);
    STAGEPT(t0+1, 1, 1);
    MFMA_SET(a0_, b0_);
    SCHED0(); VMST(); BARR(); SCHED0();
    READ_SET(a0_, b0_, 1, 0);
    if (!last) STAGEPT(t0+2, 0, 0);
    MFMA_SET(a1_, b1_);
    SCHED0(); if (last) { VMWAIT(0); } else { VMST(); } BARR(); SCHED0();
    READ_SET(a1_, b1_, 1, 1);
    if (!last) STAGEPT(t0+2, 1, 0);
    MFMA_SET(a0_, b0_);
    SCHED0(); if (!last) { VMST(); } BARR(); SCHED0();
    if (!last){ READ_SET(a0_, b0_, 0, 0); STAGEPT(t0+3, 0, 1); }
    MFMA_SET(a1_, b1_);
    if (!last){ SCHED0(); VMST(); BARR(); SCHED0(); }
  }

  #pragma unroll
  for (int mi=0; mi<MREP; mi++)
    #pragma unroll
    for (int n=0; n<NF; n++)
      #pragma unroll
      for (int r=0;r<4;r++){
        int row = m0 + (wm*MREP+mi)*16 + g*4 + r;
        int col = n0 + wn*(NF*16) + n*16 + ln;
        if constexpr (__is_same(OT, u16))
          C[(size_t)row*N + col] = (u16)f2bfbits(acc[mi][n][r]);
        else
          C[(size_t)row*N + col] = acc[mi][n][r];
      }
  #undef AREG
  #undef BREG
  #undef STAGEPT
  #undef READ_SET
  #undef MFMA_SET
  #undef BARR
  #undef VMST
}

// ---------------- flash attention v6: QK(i+1) || softmax(i) pipeline ---------
__global__ __launch_bounds__(256) void flash_attn(const u16* __restrict__ Qn,
                                                  const u16* __restrict__ Kn,
                                                  const u16* __restrict__ Vt,
                                                  u16* __restrict__ O){
  __shared__ u16 Ks[2][64*128];
  __shared__ u16 Vs[2][128*64];

  const int h = blockIdx.y;
  const int w = threadIdx.x>>6, lane = threadIdx.x&63, ln = lane&15, g = lane>>4;
  const int kvh = h>>2;
  const u16* Qh = Qn + (size_t)h*S_LEN*HD;
  const u16* Kh = Kn + (size_t)kvh*S_LEN*HD;
  const u16* Vh = Vt + (size_t)kvh*HD*S_LEN;

  const int krow_w = w*4 + g;
  const int ksw    = ((krow_w)&7)<<4;
  const int kcol   = ((ln*16) ^ ksw) >> 1;
  const int vrow_w = w*8 + (lane>>3);
  const int vsw    = ((lane>>3)&7)<<4;
  const int vcol   = (((lane&7)*16) ^ vsw) >> 1;

  #define STAGE_K(bufi, t) { \
    int kv0_ = (t)*64; \
    _Pragma("unroll") \
    for (int p=0;p<4;p++){ \
      const u16* ga = Kh + (size_t)(kv0_ + p*16 + krow_w)*HD + kcol; \
      GLOAD16(ga, (char*)&Ks[bufi][0] + p*4096 + w*1024); \
    } \
  }
  #define STAGE_V(bufi, t) { \
    int kv0_ = (t)*64; \
    _Pragma("unroll") \
    for (int p=0;p<4;p++){ \
      const u16* gv = Vh + (size_t)(p*32 + vrow_w)*S_LEN + kv0_ + vcol; \
      GLOAD16(gv, (char*)&Vs[bufi][0] + p*4096 + w*1024); \
    } \
  }
  #define QKT(dst, buf) { \
    _Pragma("unroll") for (int mt=0; mt<4; mt++){ \
      short8 kf[4]; \
      _Pragma("unroll") for (int c=0;c<4;c++) \
        kf[c] = *(const short8*)((const char*)&Ks[buf][0] \
                    + (mt*16+ln)*256 + ((c*64 + g*16) ^ ((ln&7)<<4))); \
      f32x4 qacc = (f32x4){0.f,0.f,0.f,0.f}; \
      __builtin_amdgcn_s_setprio(1); \
      _Pragma("unroll") for (int c=0;c<4;c++) \
        qacc = __builtin_amdgcn_mfma_f32_16x16x32_bf16(kf[c], qf[c], qacc, 0,0,0); \
      __builtin_amdgcn_s_setprio(0); \
      dst[mt] = qacc; \
    } }

  #define TILE_BODY(i, SC, SN) { \
    VMWAIT(0); \
    __builtin_amdgcn_s_barrier(); \
    if ((i)+1 < nt){ \
      QKT(SN, ((i)+1)&1); \
      if ((i)+2 < nt) STAGE_K(((i)+2)&1, (i)+2); \
      STAGE_V(((i)+1)&1, (i)+1); \
    } \
    const int kv0 = (i)*64; \
    float p[4][4]; \
    float mtile = -1e30f; \
    if ((i) < qb){ \
      _Pragma("unroll") for (int mt=0; mt<4; mt++) \
        _Pragma("unroll") for (int r=0;r<4;r++){ \
          p[mt][r] = SC[mt][r]; \
          mtile = fmaxf(mtile, SC[mt][r]); \
        } \
    } else { \
      _Pragma("unroll") for (int mt=0; mt<4; mt++) \
        _Pragma("unroll") for (int r=0;r<4;r++){ \
          int kv = kv0 + mt*16 + 4*g + r; \
          float sv = (kv <= qrow) ? SC[mt][r] : -1e30f; \
          p[mt][r] = sv; \
          mtile = fmaxf(mtile, sv); \
        } \
    } \
    mtile = fmaxf(mtile, __shfl_xor(mtile, 16, 64)); \
    mtile = fmaxf(mtile, __shfl_xor(mtile, 32, 64)); \
    bool defer = __all(mtile <= m_run + 11.5416f); \
    float m_new = defer ? m_run : fmaxf(m_run, mtile); \
    float l_tile = 0.f; \
    _Pragma("unroll") for (int mt=0; mt<4; mt++) \
      _Pragma("unroll") for (int r=0;r<4;r++){ \
        float e = exp2f(p[mt][r] - m_new); \
        p[mt][r] = e; \
        l_tile += e; \
      } \
    l_tile += __shfl_xor(l_tile, 16, 64); \
    l_tile += __shfl_xor(l_tile, 32, 64); \
    if (defer){ \
      l_run += l_tile; \
    } else { \
      float alpha = exp2f(m_run - m_new); \
      l_run = l_run*alpha + l_tile; \
      m_run = m_new; \
      _Pragma("unroll") for (int dt=0;dt<8;dt++) ot[dt] *= alpha; \
    } \
    short8 pf[2]; \
    _Pragma("unroll") for (int ks2=0; ks2<2; ks2++){ \
      unsigned pk00 = cvtpk(p[2*ks2  ][0], p[2*ks2  ][1]); \
      unsigned pk01 = cvtpk(p[2*ks2  ][2], p[2*ks2  ][3]); \
      unsigned pk10 = cvtpk(p[2*ks2+1][0], p[2*ks2+1][1]); \
      unsigned pk11 = cvtpk(p[2*ks2+1][2], p[2*ks2+1][3]); \
      int src0 = (((2*g  )&3)<<4) | ln; \
      int src1 = (((2*g+1)&3)<<4) | ln; \
      unsigned t00 = (unsigned)__shfl((int)pk00, src0, 64); \
      unsigned t10 = (unsigned)__shfl((int)pk10, src0, 64); \
      unsigned t01 = (unsigned)__shfl((int)pk01, src0, 64); \
      unsigned t11 = (unsigned)__shfl((int)pk11, src0, 64); \
      unsigned u00 = (unsigned)__shfl((int)pk00, src1, 64); \
      unsigned u10 = (unsigned)__shfl((int)pk10, src1, 64); \
      unsigned u01 = (unsigned)__shfl((int)pk01, src1, 64); \
      unsigned u11 = (unsigned)__shfl((int)pk11, src1, 64); \
      bool hiv = (g >= 2); \
      union { unsigned u[4]; short8 s; } pw; \
      pw.u[0] = hiv ? t10 : t00; \
      pw.u[1] = hiv ? t11 : t01; \
      pw.u[2] = hiv ? u10 : u00; \
      pw.u[3] = hiv ? u11 : u01; \
      pf[ks2] = pw.s; \
    } \
    _Pragma("unroll") for (int dt=0;dt<8;dt++){ \
      short8 vf[2]; \
      _Pragma("unroll") for (int ks2=0; ks2<2; ks2++) \
        vf[ks2] = *(const short8*)((const char*)&Vs[(i)&1][0] \
                    + (dt*16+ln)*128 + ((ks2*64 + g*16) ^ ((ln&7)<<4))); \
      __builtin_amdgcn_s_setprio(1); \
      _Pragma("unroll") for (int ks2=0; ks2<2; ks2++) \
        ot[dt] = __builtin_amdgcn_mfma_f32_16x16x32_bf16(vf[ks2], pf[ks2], ot[dt], 0,0,0); \
      __builtin_amdgcn_s_setprio(0); \
    } \
  }

  #pragma unroll 1
  for (int ph=0; ph<2; ph++){
    const int qb = ph ? (31 - blockIdx.x) : blockIdx.x;
    const int q0 = qb*64;
    const int qrow = q0 + w*16 + ln;

    short8 qf[4];
    #pragma unroll
    for (int c=0;c<4;c++)
      qf[c] = *(const short8*)(Qh + (size_t)qrow*HD + c*32 + g*8);

    f32x4 ot[8];
    #pragma unroll
    for (int dt=0;dt<8;dt++) ot[dt] = (f32x4){0.f,0.f,0.f,0.f};
    float m_run = -1e30f, l_run = 0.f;

    const int nt = qb + 1;

    STAGE_K(0, 0); STAGE_V(0, 0);
    if (nt > 1) STAGE_K(1, 1);
    VMWAIT(0);
    __builtin_amdgcn_s_barrier();

    f32x4 stA[4], stB[4];
    QKT(stA, 0);

    #pragma unroll 1
    for (int i=0; i<nt; i+=2){
      TILE_BODY(i, stA, stB);
      if (i+1 < nt) TILE_BODY(i+1, stB, stA);
    }
    __syncthreads();

    float inv = 1.0f / l_run;
    u16* orow = O + (size_t)qrow*(NH*HD) + h*HD;
    #pragma unroll
    for (int dt=0;dt<8;dt++){
      #pragma unroll
      for (int rr=0; rr<4; rr+=2){
        unsigned pkd = cvtpk(ot[dt][rr]*inv, ot[dt][rr+1]*inv);
        *(unsigned*)(orow + dt*16 + g*4 + rr) = pkd;
      }
    }
  }
  #undef STAGE_K
  #undef STAGE_V
  #undef QKT
  #undef TILE_BODY
}

// ---------------- host ----------------
extern "C" void kernel_launch(void* const* d_in, const int* in_sizes, int n_in,
                              void* d_out, int out_size, void* d_ws, size_t ws_size,
                              hipStream_t stream){
  (void)in_sizes; (void)n_in; (void)out_size; (void)ws_size;
  const float* hs   = (const float*)d_in[0];
  const float* cosb = (const float*)d_in[1];
  const float* sinb = (const float*)d_in[2];
  const float* Wq   = (const float*)d_in[3];
  const float* Wk   = (const float*)d_in[4];
  const float* Wv   = (const float*)d_in[5];
  const float* Wo   = (const float*)d_in[6];
  const float* qw   = (const float*)d_in[7];
  const float* kw   = (const float*)d_in[8];
  float* out = (float*)d_out;

  char* ws = (char*)d_ws;
  // layout (bytes), total 142606336 == previously proven footprint:
  u16* Xb    = (u16*)(ws);                 // [0, 16.8M)   X bf16
  u16* WQKV  = (u16*)(ws + 16777216);      // [16.8M, 67.1M)  Wq|Wk|Wv bf16
  u16* Qn    = (u16*)(ws + 67108864);      // [67.1M, 83.9M)
  u16* Kn    = (u16*)(ws + 83886080);      // [83.9M, 88.1M)
  u16* Vt    = (u16*)(ws + 88080384);      // [88.1M, 92.3M)
  u16* attnB = (u16*)(ws + 92274688);      // [92.3M, 109.1M)
  u16* Wob   = (u16*)(ws + 109051904);     // [109.1M, 142.6M)  own region now

  // 1. convert X + Wq|Wk|Wv + Wo in one launch (5 segments)
  cvt_all<<<dim3(8192, 5), 256, 0, stream>>>(hs, Wq, Wk, Wv, Wo, Xb, WQKV, Wob);
  // 2. GEMM1 fused: QKV proj + RMSNorm + RoPE + V-transpose -> Qn/Kn/Vt
  //    128x384 tiles (3 heads per tile), 16x16 = 256 blocks
  gemm1_fused<<<256, 512, 0, stream>>>(Xb, WQKV, cosb, sinb, qw, kw, Qn, Kn, Vt);
  // 3. flash attention: 16 complementary pairs x 32 heads = 512 blocks
  flash_attn<<<dim3(16, NH), 256, 0, stream>>>(Qn, Kn, Vt, attnB);
  // 4. GEMM2: [2048 x 4096] x [4096 x 4096]^T -> fp32 out, 256 blocks
  gemm_4ph<128,256,float><<<256, 512, 0, stream>>>(attnB, Wob, out, HIDD, HIDD, HIDD/256);
}

// Round 17
// 324.237 us; speedup vs baseline: 1.0364x; 1.0364x over previous
//
#include <hip/hip_runtime.h>
#include <hip/hip_bf16.h>
#include <stdint.h>

#define S_LEN 2048
#define HIDD  4096
#define NH    32
#define NKV   8
#define HD    128
#define NQKV  6144   // (NH + 2*NKV) * HD
#define ATT_SCALE 0.08838834764831845f
#define LOG2E 1.4426950408889634f

typedef unsigned short u16;
typedef __attribute__((ext_vector_type(8))) short short8;
typedef __attribute__((ext_vector_type(4))) float f32x4;

__device__ __forceinline__ unsigned f2bfbits(float f){
  union{float f; unsigned u;} v; v.f = f;
  return (v.u + 0x7FFFu + ((v.u>>16)&1u)) >> 16;
}
__device__ __forceinline__ float bf2f(u16 b){
  union{unsigned u; float f;} v; v.u = ((unsigned)b)<<16;
  return v.f;
}
__device__ __forceinline__ unsigned packbf(float a, float b){
  return f2bfbits(a) | (f2bfbits(b)<<16);
}
__device__ __forceinline__ unsigned cvtpk(float lo, float hi){
  unsigned r;
  asm("v_cvt_pk_bf16_f32 %0, %1, %2" : "=v"(r) : "v"(lo), "v"(hi));
  return r;
}

#define GLOAD16(g, l) __builtin_amdgcn_global_load_lds( \
    (__attribute__((address_space(1))) void*)(g), \
    (__attribute__((address_space(3))) void*)(l), 16, 0, 0)

#define VMWAIT(n) asm volatile("s_waitcnt vmcnt(" #n ")" ::: "memory")
#define SCHED0() __builtin_amdgcn_sched_barrier(0)

// -------- fp32 -> bf16 convert, 5 segments (X, Wq, Wk, Wv, Wo), one launch --
__global__ __launch_bounds__(256) void cvt_all(const float* __restrict__ hs,
                                               const float* __restrict__ Wq,
                                               const float* __restrict__ Wk,
                                               const float* __restrict__ Wv,
                                               const float* __restrict__ Wo,
                                               u16* __restrict__ Xb,
                                               u16* __restrict__ WQKV,
                                               u16* __restrict__ Wob){
  const float* src; u16* dst; int n8;
  switch (blockIdx.y){
    case 0: src = hs; dst = Xb;                        n8 = S_LEN*HIDD/8;    break;
    case 1: src = Wq; dst = WQKV;                      n8 = NH*HD*HIDD/8;    break;
    case 2: src = Wk; dst = WQKV + (size_t)NH*HD*HIDD; n8 = NKV*HD*HIDD/8;   break;
    case 3: src = Wv; dst = WQKV + (size_t)(NH+NKV)*HD*HIDD; n8 = NKV*HD*HIDD/8; break;
    default:src = Wo; dst = Wob;                       n8 = HIDD*NH*HD/8;    break;
  }
  int i = blockIdx.x*256 + threadIdx.x;
  if (i >= n8) return;
  const float4* p = (const float4*)src;
  float4 a = p[2*i], b = p[2*i+1];
  union { unsigned u[4]; short8 s; } o;
  o.u[0] = packbf(a.x, a.y); o.u[1] = packbf(a.z, a.w);
  o.u[2] = packbf(b.x, b.y); o.u[3] = packbf(b.z, b.w);
  *(short8*)(dst + (size_t)i*8) = o.s;
}

// ============ 4-phase GEMM with register-fragment software pipeline =========
// (round-12 configuration — best measured: 45% MfmaUtil, ~1010 TF)
template<int BM, int BN, typename OT>
__global__ __launch_bounds__(512) void gemm_4ph(const u16* __restrict__ A,
                                                const u16* __restrict__ B,
                                                OT* __restrict__ C,
                                                int N, int K, int nbx){
  constexpr int MREP = BM/32;
  constexpr int NF   = BN/64;
  constexpr int AH   = BM/128;
  constexpr int ASZ  = BM*64;
  __shared__ __align__(16) char lds[4*ASZ + 65536];

  const int tid = threadIdx.x;
  const int w = tid>>6, lane = tid&63, ln = lane&15, g = lane>>4;
  const int wm = w>>2, wn = w&3;
  const int swz5 = ((ln>>3)&1)<<5;

  const int nwg = gridDim.x, flat = blockIdx.x;
  const int wg = (flat&7)*(nwg>>3) + (flat>>3);
  const int by = wg/nbx, bx = wg - by*nbx;
  const int m0 = by*BM, n0 = bx*BN;

  const int rs   = ((tid>>6)<<4) + ((tid&63)>>2);
  const int ksrc = ((tid&3)<<3) ^ (((tid>>5)&1)<<4);
  const u16* srcA[AH];
  #pragma unroll
  for (int h=0;h<AH;h++) srcA[h] = A + (size_t)(m0 + h*128 + rs)*K + ksrc;
  const u16* srcB[2];
  #pragma unroll
  for (int h=0;h<2;h++)  srcB[h] = B + (size_t)(n0 + h*128 + rs)*K + ksrc;

  #define AREG(bf,kh) (lds + ((bf)*2 + (kh))*ASZ)
  #define BREG(bf,kh) (lds + 4*ASZ + ((bf)*2 + (kh))*16384)

  #define STAGEPT(t, kh, bf) { const int off_ = (t)*64 + (kh)*32;                 \
    _Pragma("unroll") for (int h=0;h<AH;h++)                                      \
      GLOAD16(srcA[h]+off_, AREG(bf,kh) + h*8192 + w*1024);                       \
    _Pragma("unroll") for (int h=0;h<2;h++)                                       \
      GLOAD16(srcB[h]+off_, BREG(bf,kh) + h*8192 + w*1024); }

  f32x4 acc[MREP][NF];
  #pragma unroll
  for (int m=0;m<MREP;m++)
    #pragma unroll
    for (int n=0;n<NF;n++) acc[m][n] = (f32x4){0.f,0.f,0.f,0.f};
  short8 a0_[MREP], b0_[NF], a1_[MREP], b1_[NF];

  #define READ_SET(aset, bset, bf, kh) {                                          \
    _Pragma("unroll") for (int n=0;n<NF;n++)                                      \
      bset[n] = *(const short8*)(BREG(bf,kh) + (wn*NF+n)*1024 + ln*64 + ((g*16)^swz5)); \
    _Pragma("unroll") for (int m=0;m<MREP;m++)                                    \
      aset[m] = *(const short8*)(AREG(bf,kh) + (wm*MREP+m)*1024 + ln*64 + ((g*16)^swz5)); }
  #define MFMA_SET(aset, bset) { __builtin_amdgcn_s_setprio(1);                   \
    _Pragma("unroll") for (int m=0;m<MREP;m++)                                    \
      _Pragma("unroll") for (int n=0;n<NF;n++)                                    \
        acc[m][n] = __builtin_amdgcn_mfma_f32_16x16x32_bf16(aset[m], bset[n], acc[m][n], 0,0,0); \
    __builtin_amdgcn_s_setprio(0); }
  #define BARR() __builtin_amdgcn_s_barrier()
  #define VMST() do{ if constexpr (AH==2) { VMWAIT(4); } else { VMWAIT(3); } }while(0)

  STAGEPT(0,0,0); STAGEPT(0,1,0); STAGEPT(1,0,1);
  VMWAIT(0); BARR(); SCHED0();
  READ_SET(a0_, b0_, 0, 0);

  const int NIT = K>>7;
  #pragma unroll 1
  for (int it=0; it<NIT; ++it){
    const bool last = (it == NIT-1);
    const int t0 = 2*it;
    READ_SET(a1_, b1_, 0, 1);
    STAGEPT(t0+1, 1, 1);
    MFMA_SET(a0_, b0_);
    SCHED0(); VMST(); BARR(); SCHED0();
    READ_SET(a0_, b0_, 1, 0);
    if (!last) STAGEPT(t0+2, 0, 0);
    MFMA_SET(a1_, b1_);
    SCHED0(); if (last) { VMWAIT(0); } else { VMST(); } BARR(); SCHED0();
    READ_SET(a1_, b1_, 1, 1);
    if (!last) STAGEPT(t0+2, 1, 0);
    MFMA_SET(a0_, b0_);
    SCHED0(); if (!last) { VMST(); } BARR(); SCHED0();
    if (!last){ READ_SET(a0_, b0_, 0, 0); STAGEPT(t0+3, 0, 1); }
    MFMA_SET(a1_, b1_);
    if (!last){ SCHED0(); VMST(); BARR(); SCHED0(); }
  }

  #pragma unroll
  for (int mi=0; mi<MREP; mi++)
    #pragma unroll
    for (int n=0; n<NF; n++)
      #pragma unroll
      for (int r=0;r<4;r++){
        int row = m0 + (wm*MREP+mi)*16 + g*4 + r;
        int col = n0 + wn*(NF*16) + n*16 + ln;
        if constexpr (__is_same(OT, u16))
          C[(size_t)row*N + col] = (u16)f2bfbits(acc[mi][n][r]);
        else
          C[(size_t)row*N + col] = acc[mi][n][r];
      }
  #undef AREG
  #undef BREG
  #undef STAGEPT
  #undef READ_SET
  #undef MFMA_SET
  #undef BARR
  #undef VMST
}

// ---------------- RMSNorm + RoPE + layout (bf16 QKV input) -------------------
__global__ __launch_bounds__(256) void norm_rope(const u16* __restrict__ QKVb,
                                                 const float* __restrict__ cosb,
                                                 const float* __restrict__ sinb,
                                                 const float* __restrict__ qw,
                                                 const float* __restrict__ kw,
                                                 u16* __restrict__ Qn,
                                                 u16* __restrict__ Kn,
                                                 u16* __restrict__ Vt){
  int w = threadIdx.x>>6, lane = threadIdx.x&63;
  int row = blockIdx.x*4 + w;              // 0 .. S*48-1
  int s = row / 48, slot = row - s*48;
  const u16* src = QKVb + (size_t)s*NQKV + slot*HD;
  float x0 = bf2f(src[lane]), x1 = bf2f(src[lane+64]);
  if (slot < 40){
    float ss = x0*x0 + x1*x1;
    #pragma unroll
    for (int off=1; off<64; off<<=1) ss += __shfl_xor(ss, off, 64);
    float r = rsqrtf(ss*(1.0f/128.0f) + 1e-6f);
    const float* wgt = (slot < 32) ? qw : kw;
    float y0 = x0*r*wgt[lane], y1 = x1*r*wgt[lane+64];
    float c0 = cosb[(size_t)s*HD+lane], c1 = cosb[(size_t)s*HD+lane+64];
    float s0 = sinb[(size_t)s*HD+lane], s1 = sinb[(size_t)s*HD+lane+64];
    float o0 = y0*c0 - y1*s0;
    float o1 = y1*c1 + y0*s1;
    float sc = (slot < 32) ? (ATT_SCALE*LOG2E) : 1.0f;
    u16* dst = (slot < 32) ? (Qn + ((size_t)slot*S_LEN + s)*HD)
                           : (Kn + ((size_t)(slot-32)*S_LEN + s)*HD);
    dst[lane]    = (u16)f2bfbits(o0*sc);
    dst[lane+64] = (u16)f2bfbits(o1*sc);
  } else {
    int kvh = slot - 40;
    u16* dst = Vt + (size_t)kvh*HD*S_LEN + s;
    dst[(size_t)lane*S_LEN]      = (u16)f2bfbits(x0);
    dst[(size_t)(lane+64)*S_LEN] = (u16)f2bfbits(x1);
  }
}

// ---------------- flash attention v5 (round-12 configuration) ----------------
__global__ __launch_bounds__(256) void flash_attn(const u16* __restrict__ Qn,
                                                  const u16* __restrict__ Kn,
                                                  const u16* __restrict__ Vt,
                                                  u16* __restrict__ O){
  __shared__ u16 Ks[2][64*128];   // [kv][d] swizzled, 16KB each
  __shared__ u16 Vs[2][128*64];   // [d][kv] swizzled, 16KB each

  const int h = blockIdx.y;
  const int w = threadIdx.x>>6, lane = threadIdx.x&63, ln = lane&15, g = lane>>4;
  const int kvh = h>>2;                        // NH/NKV = 4
  const u16* Qh = Qn + (size_t)h*S_LEN*HD;
  const u16* Kh = Kn + (size_t)kvh*S_LEN*HD;
  const u16* Vh = Vt + (size_t)kvh*HD*S_LEN;

  const int krow_w = w*4 + g;
  const int ksw    = ((krow_w)&7)<<4;
  const int kcol   = ((ln*16) ^ ksw) >> 1;
  const int vrow_w = w*8 + (lane>>3);
  const int vsw    = ((lane>>3)&7)<<4;
  const int vcol   = (((lane&7)*16) ^ vsw) >> 1;

  #define STAGE_K(bufi, t) { \
    int kv0_ = (t)*64; \
    _Pragma("unroll") \
    for (int p=0;p<4;p++){ \
      const u16* ga = Kh + (size_t)(kv0_ + p*16 + krow_w)*HD + kcol; \
      GLOAD16(ga, (char*)&Ks[bufi][0] + p*4096 + w*1024); \
    } \
  }
  #define STAGE_V(bufi, t) { \
    int kv0_ = (t)*64; \
    _Pragma("unroll") \
    for (int p=0;p<4;p++){ \
      const u16* gv = Vh + (size_t)(p*32 + vrow_w)*S_LEN + kv0_ + vcol; \
      GLOAD16(gv, (char*)&Vs[bufi][0] + p*4096 + w*1024); \
    } \
  }

  #pragma unroll 1
  for (int ph=0; ph<2; ph++){
    const int qb = ph ? (31 - blockIdx.x) : blockIdx.x;
    const int q0 = qb*64;
    const int qrow = q0 + w*16 + ln;

    short8 qf[4];
    #pragma unroll
    for (int c=0;c<4;c++)
      qf[c] = *(const short8*)(Qh + (size_t)qrow*HD + c*32 + g*8);

    f32x4 ot[8];
    #pragma unroll
    for (int dt=0;dt<8;dt++) ot[dt] = (f32x4){0.f,0.f,0.f,0.f};
    float m_run = -1e30f, l_run = 0.f;

    const int nt = qb + 1;

    STAGE_K(0, 0); STAGE_V(0, 0);
    __syncthreads();

    for (int t=0; t<nt; ++t){
      const int cur = t&1;
      if (t+1 < nt) STAGE_K(cur^1, t+1);
      const int kv0 = t*64;

      f32x4 st[4];
      #pragma unroll
      for (int mt=0; mt<4; mt++){
        short8 kf[4];
        #pragma unroll
        for (int c=0;c<4;c++)
          kf[c] = *(const short8*)((const char*)&Ks[cur][0]
                      + (mt*16+ln)*256 + ((c*64 + g*16) ^ ((ln&7)<<4)));
        f32x4 acc = (f32x4){0.f,0.f,0.f,0.f};
        __builtin_amdgcn_s_setprio(1);
        #pragma unroll
        for (int c=0;c<4;c++)
          acc = __builtin_amdgcn_mfma_f32_16x16x32_bf16(kf[c], qf[c], acc, 0,0,0);
        __builtin_amdgcn_s_setprio(0);
        st[mt] = acc;
      }

      if (t+1 < nt) STAGE_V(cur^1, t+1);

      float p[4][4];
      float mtile = -1e30f;
      if (t < qb){
        #pragma unroll
        for (int mt=0; mt<4; mt++)
          #pragma unroll
          for (int r=0;r<4;r++){
            p[mt][r] = st[mt][r];
            mtile = fmaxf(mtile, st[mt][r]);
          }
      } else {
        #pragma unroll
        for (int mt=0; mt<4; mt++)
          #pragma unroll
          for (int r=0;r<4;r++){
            int kv = kv0 + mt*16 + 4*g + r;
            float sv = (kv <= qrow) ? st[mt][r] : -1e30f;
            p[mt][r] = sv;
            mtile = fmaxf(mtile, sv);
          }
      }
      mtile = fmaxf(mtile, __shfl_xor(mtile, 16, 64));
      mtile = fmaxf(mtile, __shfl_xor(mtile, 32, 64));

      bool defer = __all(mtile <= m_run + 11.5416f);
      float m_new = defer ? m_run : fmaxf(m_run, mtile);

      float l_tile = 0.f;
      #pragma unroll
      for (int mt=0; mt<4; mt++)
        #pragma unroll
        for (int r=0;r<4;r++){
          float e = exp2f(p[mt][r] - m_new);
          p[mt][r] = e;
          l_tile += e;
        }
      l_tile += __shfl_xor(l_tile, 16, 64);
      l_tile += __shfl_xor(l_tile, 32, 64);
      if (defer){
        l_run += l_tile;
      } else {
        float alpha = exp2f(m_run - m_new);
        l_run = l_run*alpha + l_tile;
        m_run = m_new;
        #pragma unroll
        for (int dt=0;dt<8;dt++) ot[dt] *= alpha;
      }

      short8 pf[2];
      #pragma unroll
      for (int ks2=0; ks2<2; ks2++){
        unsigned pk00 = cvtpk(p[2*ks2  ][0], p[2*ks2  ][1]);
        unsigned pk01 = cvtpk(p[2*ks2  ][2], p[2*ks2  ][3]);
        unsigned pk10 = cvtpk(p[2*ks2+1][0], p[2*ks2+1][1]);
        unsigned pk11 = cvtpk(p[2*ks2+1][2], p[2*ks2+1][3]);
        int src0 = (((2*g  )&3)<<4) | ln;
        int src1 = (((2*g+1)&3)<<4) | ln;
        unsigned t00 = (unsigned)__shfl((int)pk00, src0, 64);
        unsigned t10 = (unsigned)__shfl((int)pk10, src0, 64);
        unsigned t01 = (unsigned)__shfl((int)pk01, src0, 64);
        unsigned t11 = (unsigned)__shfl((int)pk11, src0, 64);
        unsigned u00 = (unsigned)__shfl((int)pk00, src1, 64);
        unsigned u10 = (unsigned)__shfl((int)pk10, src1, 64);
        unsigned u01 = (unsigned)__shfl((int)pk01, src1, 64);
        unsigned u11 = (unsigned)__shfl((int)pk11, src1, 64);
        bool hiv = (g >= 2);
        union { unsigned u[4]; short8 s; } pw;
        pw.u[0] = hiv ? t10 : t00;
        pw.u[1] = hiv ? t11 : t01;
        pw.u[2] = hiv ? u10 : u00;
        pw.u[3] = hiv ? u11 : u01;
        pf[ks2] = pw.s;
      }

      #pragma unroll
      for (int dt=0;dt<8;dt++){
        short8 vf[2];
        #pragma unroll
        for (int ks2=0; ks2<2; ks2++)
          vf[ks2] = *(const short8*)((const char*)&Vs[cur][0]
                      + (dt*16+ln)*128 + ((ks2*64 + g*16) ^ ((ln&7)<<4)));
        __builtin_amdgcn_s_setprio(1);
        #pragma unroll
        for (int ks2=0; ks2<2; ks2++)
          ot[dt] = __builtin_amdgcn_mfma_f32_16x16x32_bf16(vf[ks2], pf[ks2], ot[dt], 0,0,0);
        __builtin_amdgcn_s_setprio(0);
      }
      __syncthreads();
    }

    float inv = 1.0f / l_run;
    u16* orow = O + (size_t)qrow*(NH*HD) + h*HD;
    #pragma unroll
    for (int dt=0;dt<8;dt++){
      #pragma unroll
      for (int rr=0; rr<4; rr+=2){
        unsigned pkd = cvtpk(ot[dt][rr]*inv, ot[dt][rr+1]*inv);
        *(unsigned*)(orow + dt*16 + g*4 + rr) = pkd;
      }
    }
  }
  #undef STAGE_K
  #undef STAGE_V
}

// ---------------- host ----------------
extern "C" void kernel_launch(void* const* d_in, const int* in_sizes, int n_in,
                              void* d_out, int out_size, void* d_ws, size_t ws_size,
                              hipStream_t stream){
  (void)in_sizes; (void)n_in; (void)out_size; (void)ws_size;
  const float* hs   = (const float*)d_in[0];
  const float* cosb = (const float*)d_in[1];
  const float* sinb = (const float*)d_in[2];
  const float* Wq   = (const float*)d_in[3];
  const float* Wk   = (const float*)d_in[4];
  const float* Wv   = (const float*)d_in[5];
  const float* Wo   = (const float*)d_in[6];
  const float* qw   = (const float*)d_in[7];
  const float* kw   = (const float*)d_in[8];
  float* out = (float*)d_out;

  char* ws = (char*)d_ws;
  // lifetimes: {Xb,WQKV} die after GEMM1 -> Qn/Kn/Vt overlay them (written by
  // norm_rope, which runs after GEMM1). Wob has its own region so Wo converts
  // up-front in cvt_all. QKVb dies after norm_rope. Total = 142606336 B.
  u16* Xb    = (u16*)(ws);                 // [0, 16.8M)
  u16* WQKV  = (u16*)(ws + 16777216);      // [16.8M, 67.1M)
  u16* QKVb  = (u16*)(ws + 67108864);      // [67.1M, 92.3M)
  u16* attnB = (u16*)(ws + 92274688);      // [92.3M, 109.1M)
  u16* Wob   = (u16*)(ws + 109051904);     // [109.1M, 142.6M)
  u16* Qn    = (u16*)(ws);                 // overlay dead Xb      [0, 16.8M)
  u16* Kn    = (u16*)(ws + 16777216);      // overlay dead WQKV    [16.8M, 21.0M)
  u16* Vt    = (u16*)(ws + 20971520);      // overlay dead WQKV    [21.0M, 25.2M)

  // 1. convert X + Wq|Wk|Wv + Wo in one launch (5 segments)
  cvt_all<<<dim3(8192, 5), 256, 0, stream>>>(hs, Wq, Wk, Wv, Wo, Xb, WQKV, Wob);
  // 2. GEMM1: [2048 x 4096] x [6144 x 4096]^T -> bf16 QKV, 256 blocks
  gemm_4ph<256,192,u16><<<256, 512, 0, stream>>>(Xb, WQKV, QKVb, NQKV, HIDD, NQKV/192);
  // 3. RMSNorm + RoPE + relayout (bf16 in) -> Qn/Kn/Vt (over dead Xb/WQKV)
  norm_rope<<<(S_LEN*48)/4, 256, 0, stream>>>(QKVb, cosb, sinb, qw, kw, Qn, Kn, Vt);
  // 4. flash attention: 16 complementary pairs x 32 heads = 512 blocks
  flash_attn<<<dim3(16, NH), 256, 0, stream>>>(Qn, Kn, Vt, attnB);
  // 5. GEMM2: [2048 x 4096] x [4096 x 4096]^T -> fp32 out, 256 blocks
  gemm_4ph<128,256,float><<<256, 512, 0, stream>>>(attnB, Wob, out, HIDD, HIDD, HIDD/256);
}